// Round 9
// baseline (381.517 us; speedup 1.0000x reference)
//
#include <hip/hip_runtime.h>
#include <hip/hip_fp16.h>
#include <math.h>

#define N_NODES 100000
#define N_EDGES 1600000
#define EP (N_EDGES + N_NODES)   // edges incl self-loops
#define HID 64
#define SCAN_B 1024
#define NB ((N_NODES + SCAN_B - 1) / SCAN_B)     // 98 blocks (node scan)
#define NCHUNK 512                               // pass-A chunks
#define CE (N_EDGES / NCHUNK)                    // 3125 edges per chunk (exact)
#define NBUCK 391                                // buckets of 256 keys
#define NHIST (NBUCK * NCHUNK)                   // 200192
#define NHB ((NHIST + SCAN_B - 1) / SCAN_B)      // 196 blocks (hist scan)
#define NTILE (N_NODES / 16)                     // 6250 MFMA tiles (exact)

typedef _Float16 half8_t __attribute__((ext_vector_type(8)));
typedef _Float16 half4_t __attribute__((ext_vector_type(4)));
typedef float f32x4_t __attribute__((ext_vector_type(4)));

// ================= bucketed CSR build (no global atomics) =================

__global__ __launch_bounds__(256)
void hist_kernel(const int* __restrict__ dst, int* __restrict__ h) {
    __shared__ int hist[NBUCK];
    const int tid = threadIdx.x, c = blockIdx.x;
    for (int b = tid; b < NBUCK; b += 256) hist[b] = 0;
    __syncthreads();
    for (int e = c * CE + tid; e < (c + 1) * CE; e += 256)
        atomicAdd(&hist[dst[e] >> 8], 1);
    __syncthreads();
    for (int b = tid; b < NBUCK; b += 256) h[b * NCHUNK + c] = hist[b];
}

__global__ void scang_block(const int* __restrict__ in, int* __restrict__ out,
                            int* __restrict__ bsum, int n) {
    __shared__ int wsum[16];
    int tid = threadIdx.x, lane = tid & 63, wid = tid >> 6;
    int i = blockIdx.x * SCAN_B + tid;
    int x = (i < n) ? in[i] : 0;
#pragma unroll
    for (int off = 1; off < 64; off <<= 1) {
        int y = __shfl_up(x, off, 64);
        if (lane >= off) x += y;
    }
    if (lane == 63) wsum[wid] = x;
    __syncthreads();
    if (tid == 0) {
        int s = 0;
#pragma unroll
        for (int j = 0; j < 16; ++j) { int t2 = wsum[j]; wsum[j] = s; s += t2; }
    }
    __syncthreads();
    int inc = wsum[wid] + x;
    if (i < n) out[i + 1] = inc;
    if (tid == SCAN_B - 1) bsum[blockIdx.x] = inc;
}

__global__ void scang_bsum(int* __restrict__ bsum, int nb) {   // nb <= 256
    __shared__ int tmp[256];
    int t = threadIdx.x;
    tmp[t] = (t < nb) ? bsum[t] : 0;
    __syncthreads();
    for (int off = 1; off < 256; off <<= 1) {
        int v = (t >= off) ? tmp[t - off] : 0;
        __syncthreads();
        tmp[t] += v;
        __syncthreads();
    }
    if (t < nb) bsum[t] = (t == 0) ? 0 : tmp[t - 1];
}

__global__ void scang_add(int* __restrict__ out, const int* __restrict__ bsum, int n) {
    int i = blockIdx.x * SCAN_B + threadIdx.x;
    if (i == 0) out[0] = 0;
    if (i < n) out[i + 1] += bsum[blockIdx.x];
}

__global__ __launch_bounds__(256)
void scatter_kernel(const int* __restrict__ src, const int* __restrict__ dst,
                    const int* __restrict__ baseA, unsigned long long* __restrict__ ebuf) {
    __shared__ int cur[NBUCK];
    const int tid = threadIdx.x, c = blockIdx.x;
    for (int b = tid; b < NBUCK; b += 256) cur[b] = baseA[b * NCHUNK + c];
    __syncthreads();
    for (int e = c * CE + tid; e < (c + 1) * CE; e += 256) {
        int d = dst[e], s = src[e];
        int p = atomicAdd(&cur[d >> 8], 1);
        ebuf[p] = (unsigned long long)(unsigned)d | ((unsigned long long)(unsigned)s << 32);
    }
}

__global__ __launch_bounds__(256)
void rank_kernel(const unsigned long long* __restrict__ ebuf, const int* __restrict__ baseA,
                 int* __restrict__ rank, int* __restrict__ deg) {
    __shared__ int cnt[256];
    const int tid = threadIdx.x, b = blockIdx.x;
    cnt[tid] = 0;
    __syncthreads();
    const int R0 = baseA[b * NCHUNK], R1 = baseA[(b + 1) * NCHUNK];
    for (int pos = R0 + tid; pos < R1; pos += 256) {
        int d = (int)(unsigned)ebuf[pos];
        rank[pos] = atomicAdd(&cnt[d & 255], 1);
    }
    __syncthreads();
    int k = b * 256 + tid;
    if (k < N_NODES) deg[k] = cnt[tid];
}

// ---------------- node scan over (deg+1) (+ fused dinv) ----------------

__global__ void scan_block_kernel(const int* __restrict__ deg, int* __restrict__ rowptr,
                                  int* __restrict__ bsum, float* __restrict__ dinv) {
    __shared__ int wsum[16];
    int tid = threadIdx.x, lane = tid & 63, wid = tid >> 6;
    int i = blockIdx.x * SCAN_B + tid;
    int v = (i < N_NODES) ? deg[i] : 0;
    int x = (i < N_NODES) ? (v + 1) : 0;   // +1 self-loop slot
#pragma unroll
    for (int off = 1; off < 64; off <<= 1) {
        int y = __shfl_up(x, off, 64);
        if (lane >= off) x += y;
    }
    if (lane == 63) wsum[wid] = x;
    __syncthreads();
    if (tid == 0) {
        int s = 0;
#pragma unroll
        for (int j = 0; j < 16; ++j) { int t2 = wsum[j]; wsum[j] = s; s += t2; }
    }
    __syncthreads();
    int inc = wsum[wid] + x;
    if (i < N_NODES) {
        rowptr[i + 1] = inc;
        dinv[i] = rsqrtf((float)(v + 1));
    }
    if (tid == SCAN_B - 1) bsum[blockIdx.x] = inc;
}

__global__ void add_off_kernel(int* __restrict__ rowptr, const int* __restrict__ bsum,
                               int* __restrict__ csr_src) {
    int i = blockIdx.x * SCAN_B + threadIdx.x;
    if (i == 0) rowptr[0] = 0;
    if (i < N_NODES) {
        int rp1 = rowptr[i + 1] + bsum[blockIdx.x];
        rowptr[i + 1] = rp1;
        csr_src[rp1 - 1] = i;          // self-loop at end of node i's list
    }
    if (blockIdx.x == 0 && threadIdx.x < 64) csr_src[EP + threadIdx.x] = 0;  // pad
}

__global__ __launch_bounds__(256)
void fill_kernel(const unsigned long long* __restrict__ ebuf, const int* __restrict__ rank,
                 const int* __restrict__ rowptr, int* __restrict__ csr_src) {
    int pos = blockIdx.x * 256 + threadIdx.x;
    unsigned long long v = ebuf[pos];
    int d = (int)(unsigned)v, s = (int)(v >> 32);
    csr_src[rowptr[d] + rank[pos]] = s;
}

// ---------------- layer 1: gf = fp16( dinv * (x @ W1) ), [N][64] ----------------

__global__ void layer1_kernel(const float* __restrict__ x, const float* __restrict__ W1,
                              const float* __restrict__ dinv, __half* __restrict__ gf) {
    int idx = blockIdx.x * blockDim.x + threadIdx.x;
    if (idx >= N_NODES * HID) return;
    int n = idx >> 6, c = idx & 63;
    float v = x[n * 3 + 0] * W1[c] + x[n * 3 + 1] * W1[HID + c]
            + x[n * 3 + 2] * W1[2 * HID + c];
    gf[idx] = __float2half(v * dinv[n]);
}

// ================= fused layer: gather + hv + MFMA transform =================
// Wave = 16 nodes = one 16x64 MFMA A-tile. Gather as before (4 groups x 16
// lanes). hv = relu(di*agg+b) -> fp16 LDS tile (row stride 72 = pad 8).
// A-frag: lane(m=lane&15, kg=lane>>4) holds hv[m][kg*8+j]; B-frag: W[k][n],
// n=lane&15. 8 MFMA per tile. C: col=lane&15, row=(lane>>4)*4+reg.

__device__ __forceinline__ void gather16(const uint2* __restrict__ gf2,
                                         const int* __restrict__ rowptr,
                                         const int* __restrict__ csr,
                                         const float* __restrict__ dinv,
                                         const float4 b4, int n0, int lane,
                                         _Float16* __restrict__ tl) {
    const int g = lane >> 4, p = lane & 15;
    int rp = rowptr[n0 + min(lane, 16)];
    int begv[16], cntv[16], idxv[16];
    int end_prev = __shfl(rp, 0, 64);
#pragma unroll
    for (int i = 0; i < 16; ++i) {     // 16 independent index loads in flight
        int end = __shfl(rp, i + 1, 64);
        begv[i] = end_prev;
        cntv[i] = end - end_prev;
        end_prev = end;
        idxv[i] = csr[begv[i] + lane]; // safe: csr padded by 64
    }
#pragma unroll
    for (int i = 0; i < 16; ++i) {
        const int cnt = cntv[i], beg = begv[i], iv = idxv[i];
        float4 acc = make_float4(0.f, 0.f, 0.f, 0.f);
#pragma unroll
        for (int k = 0; k < 4; ++k) {
            int e = g + 4 * k;
            int s = __shfl(iv, e, 64);
            uint2 u = gf2[(size_t)s * 16 + p];
            __half2 h0 = *(__half2*)&u.x, h1 = *(__half2*)&u.y;
            float2 a = __half22float2(h0), b = __half22float2(h1);
            if (e < cnt) { acc.x += a.x; acc.y += a.y; acc.z += b.x; acc.w += b.y; }
        }
        if (cnt > 16) {
#pragma unroll
            for (int k = 4; k < 8; ++k) {
                int e = g + 4 * k;
                int s = __shfl(iv, e, 64);
                uint2 u = gf2[(size_t)s * 16 + p];
                __half2 h0 = *(__half2*)&u.x, h1 = *(__half2*)&u.y;
                float2 a = __half22float2(h0), b = __half22float2(h1);
                if (e < cnt) { acc.x += a.x; acc.y += a.y; acc.z += b.x; acc.w += b.y; }
            }
            if (cnt > 32) {          // rare tail
                for (int e = 32 + g; e < cnt; e += 4) {
                    int s = (e < 64) ? __shfl(iv, e, 64) : csr[beg + e];
                    uint2 u = gf2[(size_t)s * 16 + p];
                    __half2 h0 = *(__half2*)&u.x, h1 = *(__half2*)&u.y;
                    float2 a = __half22float2(h0), b = __half22float2(h1);
                    acc.x += a.x; acc.y += a.y; acc.z += b.x; acc.w += b.y;
                }
            }
        }
        acc.x += __shfl_xor(acc.x, 16, 64);
        acc.y += __shfl_xor(acc.y, 16, 64);
        acc.z += __shfl_xor(acc.z, 16, 64);
        acc.w += __shfl_xor(acc.w, 16, 64);
        acc.x += __shfl_xor(acc.x, 32, 64);
        acc.y += __shfl_xor(acc.y, 32, 64);
        acc.z += __shfl_xor(acc.z, 32, 64);
        acc.w += __shfl_xor(acc.w, 32, 64);
        if (g == 0) {
            float di = dinv[n0 + i];
            half4_t hv;
            hv[0] = (_Float16)fmaxf(fmaf(di, acc.x, b4.x), 0.0f);
            hv[1] = (_Float16)fmaxf(fmaf(di, acc.y, b4.y), 0.0f);
            hv[2] = (_Float16)fmaxf(fmaf(di, acc.z, b4.z), 0.0f);
            hv[3] = (_Float16)fmaxf(fmaf(di, acc.w, b4.w), 0.0f);
            *(half4_t*)(tl + i * 72 + p * 4) = hv;   // ds_write_b64
        }
    }
}

__global__ __launch_bounds__(256, 2)
void fused_layer_kernel(const __half* __restrict__ gf_in, const int* __restrict__ rowptr,
                        const int* __restrict__ csr, const float* __restrict__ dinv,
                        const float* __restrict__ bprev, const float* __restrict__ W,
                        __half* __restrict__ gf_out) {
    __shared__ __align__(16) _Float16 tile[4][16 * 72];
    const int lane = threadIdx.x & 63, wid = threadIdx.x >> 6;
    const int tid4 = blockIdx.x * 4 + wid;
    if (tid4 >= NTILE) return;
    const int n0 = tid4 * 16;
    _Float16* tl = &tile[wid][0];
    const float4 b4 = ((const float4*)bprev)[lane & 15];

    gather16((const uint2*)gf_in, rowptr, csr, dinv, b4, n0, lane, tl);

    // B-frags: W[k][c] fp32 -> f16, k = kg*8+j (+32 for K-half 1), c = t*16+n
    const int kg = lane >> 4, n = lane & 15;
    half8_t B[4][2];
#pragma unroll
    for (int t = 0; t < 4; ++t)
#pragma unroll
        for (int h = 0; h < 2; ++h)
#pragma unroll
            for (int j = 0; j < 8; ++j)
                B[t][h][j] = (_Float16)W[(h * 32 + kg * 8 + j) * HID + t * 16 + n];

    half8_t A0 = *(const half8_t*)(tl + n * 72 + kg * 8);
    half8_t A1 = *(const half8_t*)(tl + n * 72 + 32 + kg * 8);

    f32x4_t C[4];
#pragma unroll
    for (int t = 0; t < 4; ++t) {
        f32x4_t c = {0.f, 0.f, 0.f, 0.f};
        c = __builtin_amdgcn_mfma_f32_16x16x32_f16(A0, B[t][0], c, 0, 0, 0);
        c = __builtin_amdgcn_mfma_f32_16x16x32_f16(A1, B[t][1], c, 0, 0, 0);
        C[t] = c;
    }

    // epilogue: scale by di[row], fp16, LDS transpose, coalesced stores
    const int q = lane >> 4;
    float di4[4];
#pragma unroll
    for (int r = 0; r < 4; ++r) di4[r] = dinv[n0 + q * 4 + r];
#pragma unroll
    for (int t = 0; t < 4; ++t)
#pragma unroll
        for (int r = 0; r < 4; ++r)
            tl[(q * 4 + r) * 72 + t * 16 + n] = (_Float16)(C[t][r] * di4[r]);
    const int r2 = lane >> 2, ch = lane & 3;
    uint4 v0 = *(const uint4*)(tl + r2 * 72 + ch * 16);
    uint4 v1 = *(const uint4*)(tl + r2 * 72 + ch * 16 + 8);
    *(uint4*)((__half*)gf_out + (size_t)(n0 + r2) * HID + ch * 16) = v0;
    *(uint4*)((__half*)gf_out + (size_t)(n0 + r2) * HID + ch * 16 + 8) = v1;
}

// ================= fused final: gather + hv + MFMA (Wm1) + head =================

__global__ __launch_bounds__(256, 2)
void fused_final_kernel(const __half* __restrict__ gf_in, const int* __restrict__ rowptr,
                        const int* __restrict__ csr, const float* __restrict__ dinv,
                        const float* __restrict__ b3, const float* __restrict__ Wm1,
                        const float* __restrict__ bm1, const float* __restrict__ Wm2,
                        const float* __restrict__ bm2, float* __restrict__ out) {
    __shared__ __align__(16) _Float16 tile[4][16 * 72];
    const int lane = threadIdx.x & 63, wid = threadIdx.x >> 6;
    const int tid4 = blockIdx.x * 4 + wid;
    if (tid4 >= NTILE) return;
    const int n0 = tid4 * 16;
    _Float16* tl = &tile[wid][0];
    const float4 b4 = ((const float4*)b3)[lane & 15];

    gather16((const uint2*)gf_in, rowptr, csr, dinv, b4, n0, lane, tl);

    const int kg = lane >> 4, n = lane & 15;
    half8_t B[4][2];
#pragma unroll
    for (int t = 0; t < 4; ++t)
#pragma unroll
        for (int h = 0; h < 2; ++h)
#pragma unroll
            for (int j = 0; j < 8; ++j)
                B[t][h][j] = (_Float16)Wm1[(h * 32 + kg * 8 + j) * HID + t * 16 + n];

    half8_t A0 = *(const half8_t*)(tl + n * 72 + kg * 8);
    half8_t A1 = *(const half8_t*)(tl + n * 72 + 32 + kg * 8);

    f32x4_t C[4];
#pragma unroll
    for (int t = 0; t < 4; ++t) {
        f32x4_t c = {0.f, 0.f, 0.f, 0.f};
        c = __builtin_amdgcn_mfma_f32_16x16x32_f16(A0, B[t][0], c, 0, 0, 0);
        c = __builtin_amdgcn_mfma_f32_16x16x32_f16(A1, B[t][1], c, 0, 0, 0);
        C[t] = c;
    }

    // head: m = relu(C + bm1[c]); part[r] = sum_c m*Wm2[c]; reduce over n-lanes
    float bm14[4], wm24[4];
#pragma unroll
    for (int t = 0; t < 4; ++t) { bm14[t] = bm1[t * 16 + n]; wm24[t] = Wm2[t * 16 + n]; }
    const float bm20 = bm2[0];
    float part[4] = {0.f, 0.f, 0.f, 0.f};
#pragma unroll
    for (int t = 0; t < 4; ++t)
#pragma unroll
        for (int r = 0; r < 4; ++r)
            part[r] += fmaxf(C[t][r] + bm14[t], 0.0f) * wm24[t];
#pragma unroll
    for (int off = 1; off < 16; off <<= 1)
#pragma unroll
        for (int r = 0; r < 4; ++r) part[r] += __shfl_xor(part[r], off, 64);
    if (n == 0) {
        const int q = lane >> 4;
#pragma unroll
        for (int r = 0; r < 4; ++r)
            out[n0 + q * 4 + r] = 1.0f / (1.0f + expf(-(part[r] + bm20)));
    }
}

// ---------------- launch ----------------

extern "C" void kernel_launch(void* const* d_in, const int* in_sizes, int n_in,
                              void* d_out, int out_size, void* d_ws, size_t ws_size,
                              hipStream_t stream) {
    const float* x   = (const float*)d_in[0];
    const int*   ei  = (const int*)d_in[1];
    const float* W1  = (const float*)d_in[2];
    const float* b1  = (const float*)d_in[3];
    const float* W2  = (const float*)d_in[4];
    const float* b2  = (const float*)d_in[5];
    const float* W3  = (const float*)d_in[6];
    const float* b3  = (const float*)d_in[7];
    const float* Wm1 = (const float*)d_in[8];
    const float* bm1 = (const float*)d_in[9];
    const float* Wm2 = (const float*)d_in[10];
    const float* bm2 = (const float*)d_in[11];
    float* out = (float*)d_out;

    const int* src = ei;
    const int* dst = ei + N_EDGES;

    char* ws = (char*)d_ws;
    size_t off = 0;
    auto alloc = [&](size_t bytes) { size_t o = off; off = (off + bytes + 255) & ~(size_t)255; return (void*)(ws + o); };
    int*    deg    = (int*)alloc(4ll * N_NODES);
    int*    rowptr = (int*)alloc(4ll * (N_NODES + 1));
    int*    bsumN  = (int*)alloc(4ll * NB);
    int*    bsumA  = (int*)alloc(4ll * NHB);
    int*    histA  = (int*)alloc(4ll * NHIST);
    int*    baseA  = (int*)alloc(4ll * (NHIST + 1));
    int*    csr    = (int*)alloc(4ll * (EP + 64));       // +64 pad (zeros)
    float*  dinv   = (float*)alloc(4ll * N_NODES);
    __half* gfA    = (__half*)alloc(2ll * N_NODES * HID);
    __half* gfB    = (__half*)alloc(2ll * N_NODES * HID);
    unsigned long long* ebuf = (unsigned long long*)alloc(8ll * N_EDGES);
    int*    rank   = (int*)alloc(4ll * N_EDGES);
    (void)ws_size;

    // --- CSR build: zero global atomics ---
    hist_kernel<<<NCHUNK, 256, 0, stream>>>(dst, histA);
    scang_block<<<NHB, SCAN_B, 0, stream>>>(histA, baseA, bsumA, NHIST);
    scang_bsum<<<1, 256, 0, stream>>>(bsumA, NHB);
    scang_add<<<NHB, SCAN_B, 0, stream>>>(baseA, bsumA, NHIST);
    scatter_kernel<<<NCHUNK, 256, 0, stream>>>(src, dst, baseA, ebuf);
    rank_kernel<<<NBUCK, 256, 0, stream>>>(ebuf, baseA, rank, deg);
    scan_block_kernel<<<NB, SCAN_B, 0, stream>>>(deg, rowptr, bsumN, dinv);
    scang_bsum<<<1, 256, 0, stream>>>(bsumN, NB);
    add_off_kernel<<<NB, SCAN_B, 0, stream>>>(rowptr, bsumN, csr);
    fill_kernel<<<N_EDGES / 256, 256, 0, stream>>>(ebuf, rank, rowptr, csr);

    // --- layers (fused gather + MFMA transform) ---
    const int fblocks = (NTILE + 3) / 4;   // 1563
    layer1_kernel<<<(N_NODES * HID + 255) / 256, 256, 0, stream>>>(x, W1, dinv, gfA);
    fused_layer_kernel<<<fblocks, 256, 0, stream>>>(gfA, rowptr, csr, dinv, b1, W2, gfB);
    fused_layer_kernel<<<fblocks, 256, 0, stream>>>(gfB, rowptr, csr, dinv, b2, W3, gfA);
    fused_final_kernel<<<fblocks, 256, 0, stream>>>(gfA, rowptr, csr, dinv, b3, Wm1, bm1, Wm2, bm2, out);
}

// Round 10
// 363.808 us; speedup vs baseline: 1.0487x; 1.0487x over previous
//
#include <hip/hip_runtime.h>
#include <hip/hip_fp16.h>
#include <math.h>

#define N_NODES 100000
#define N_EDGES 1600000
#define EP (N_EDGES + N_NODES)   // edges incl self-loops
#define HID 64
#define SCAN_B 1024
#define NCHUNK 512                               // pass-A chunks
#define CE (N_EDGES / NCHUNK)                    // 3125 edges per chunk (exact)
#define NBUCK 391                                // buckets of 256 keys
#define NHIST (NBUCK * NCHUNK)                   // 200192
#define NHB ((NHIST + SCAN_B - 1) / SCAN_B)      // 196 blocks (hist scan)
#define NTILE (N_NODES / 16)                     // 6250 MFMA tiles (exact)
#define STASH 6144                               // per-bucket edge stash (avg 4092)

typedef _Float16 half8_t __attribute__((ext_vector_type(8)));
typedef _Float16 half4_t __attribute__((ext_vector_type(4)));
typedef float f32x4_t __attribute__((ext_vector_type(4)));
typedef unsigned long long u64;

// ================= bucketed CSR build (no global atomics) =================

__global__ __launch_bounds__(256)
void hist_kernel(const int* __restrict__ dst, int* __restrict__ h, int* __restrict__ csr) {
    __shared__ int hist[NBUCK];
    const int tid = threadIdx.x, c = blockIdx.x;
    for (int b = tid; b < NBUCK; b += 256) hist[b] = 0;
    __syncthreads();
    for (int e = c * CE + tid; e < (c + 1) * CE; e += 256)
        atomicAdd(&hist[dst[e] >> 8], 1);
    __syncthreads();
    for (int b = tid; b < NBUCK; b += 256) h[b * NCHUNK + c] = hist[b];
    if (c == 0 && tid < 64) csr[EP + tid] = 0;   // zero pad for gather over-read
}

__global__ void scang_block(const int* __restrict__ in, int* __restrict__ out,
                            int* __restrict__ bsum, int n) {
    __shared__ int wsum[16];
    int tid = threadIdx.x, lane = tid & 63, wid = tid >> 6;
    int i = blockIdx.x * SCAN_B + tid;
    int x = (i < n) ? in[i] : 0;
#pragma unroll
    for (int off = 1; off < 64; off <<= 1) {
        int y = __shfl_up(x, off, 64);
        if (lane >= off) x += y;
    }
    if (lane == 63) wsum[wid] = x;
    __syncthreads();
    if (tid == 0) {
        int s = 0;
#pragma unroll
        for (int j = 0; j < 16; ++j) { int t2 = wsum[j]; wsum[j] = s; s += t2; }
    }
    __syncthreads();
    int inc = wsum[wid] + x;
    if (i < n) out[i + 1] = inc;
    if (tid == SCAN_B - 1) bsum[blockIdx.x] = inc;
}

__global__ void scang_bsum(int* __restrict__ bsum, int nb) {   // nb <= 256
    __shared__ int tmp[256];
    int t = threadIdx.x;
    tmp[t] = (t < nb) ? bsum[t] : 0;
    __syncthreads();
    for (int off = 1; off < 256; off <<= 1) {
        int v = (t >= off) ? tmp[t - off] : 0;
        __syncthreads();
        tmp[t] += v;
        __syncthreads();
    }
    if (t < nb) bsum[t] = (t == 0) ? 0 : tmp[t - 1];
}

__global__ void scang_add(int* __restrict__ out, const int* __restrict__ bsum, int n) {
    int i = blockIdx.x * SCAN_B + threadIdx.x;
    if (i == 0) out[0] = 0;
    if (i < n) out[i + 1] += bsum[blockIdx.x];
}

__global__ __launch_bounds__(256)
void scatter_kernel(const int* __restrict__ src, const int* __restrict__ dst,
                    const int* __restrict__ baseA, u64* __restrict__ ebuf) {
    __shared__ int cur[NBUCK];
    const int tid = threadIdx.x, c = blockIdx.x;
    for (int b = tid; b < NBUCK; b += 256) cur[b] = baseA[b * NCHUNK + c];
    __syncthreads();
    for (int e = c * CE + tid; e < (c + 1) * CE; e += 256) {
        int d = dst[e], s = src[e];
        int p = atomicAdd(&cur[d >> 8], 1);
        ebuf[p] = (u64)(unsigned)d | ((u64)(unsigned)s << 32);
    }
}

// rankfill: per-bucket rank + cnt block-scan -> rowptr, csr (edges + self-loop),
// dinv — all in one kernel. rowptr[n] = R0 + n + intra_bucket_prefix(cnt).

__global__ __launch_bounds__(256)
void rankfill_kernel(u64* __restrict__ ebuf, const int* __restrict__ baseA,
                     int* __restrict__ rowptr, int* __restrict__ csr,
                     float* __restrict__ dinv) {
    __shared__ int cnt[256];
    __shared__ int rpl[256];
    __shared__ int wsum[4];
    __shared__ u64 stash[STASH];
    const int tid = threadIdx.x, b = blockIdx.x;
    cnt[tid] = 0;
    __syncthreads();
    const int R0 = baseA[b * NCHUNK], R1 = baseA[(b + 1) * NCHUNK];
    const int RL = R1 - R0;
    for (int off = tid; off < RL; off += 256) {
        u64 v = ebuf[R0 + off];
        int d = (int)(unsigned)v;
        int s = (int)(v >> 32);
        int key = d & 255;
        int r = atomicAdd(&cnt[key], 1);
        u64 packed = (u64)(unsigned)s | ((u64)key << 32) | ((u64)r << 40);
        if (off < STASH) stash[off] = packed;
        else ebuf[R0 + off] = packed;   // overflow fallback (≈ never)
    }
    __threadfence_block();
    __syncthreads();
    // exclusive block scan of cnt[256]
    const int lane = tid & 63, w = tid >> 6;
    int x = cnt[tid];
    int inc = x;
#pragma unroll
    for (int off = 1; off < 64; off <<= 1) {
        int y = __shfl_up(inc, off, 64);
        if (lane >= off) inc += y;
    }
    if (lane == 63) wsum[w] = inc;
    __syncthreads();
    int base = 0;
    for (int k = 0; k < 4; ++k) if (k < w) base += wsum[k];
    int pre = base + inc - x;            // exclusive prefix
    const int n = b * 256 + tid;
    const int rpn = R0 + n + pre;
    rpl[tid] = rpn;
    if (n < N_NODES) {
        rowptr[n] = rpn;
        dinv[n] = rsqrtf((float)(x + 1));
        csr[rpn + x] = n;                // self-loop at end of node's list
    }
    if (b == NBUCK - 1 && tid == 0) rowptr[N_NODES] = EP;
    __syncthreads();
    for (int off = tid; off < RL; off += 256) {
        u64 pk = (off < STASH) ? stash[off] : ebuf[R0 + off];
        int s = (int)(unsigned)pk;
        int key = (int)((pk >> 32) & 0xff);
        int r = (int)(pk >> 40);
        csr[rpl[key] + r] = s;
    }
}

// ---------------- layer 1: gf = fp16( dinv * (x @ W1) ), [N][64] ----------------

__global__ void layer1_kernel(const float* __restrict__ x, const float* __restrict__ W1,
                              const float* __restrict__ dinv, __half* __restrict__ gf) {
    int idx = blockIdx.x * blockDim.x + threadIdx.x;
    if (idx >= N_NODES * HID) return;
    int n = idx >> 6, c = idx & 63;
    float v = x[n * 3 + 0] * W1[c] + x[n * 3 + 1] * W1[HID + c]
            + x[n * 3 + 2] * W1[2 * HID + c];
    gf[idx] = __float2half(v * dinv[n]);
}

// ================= fused layer: gather + hv + MFMA transform =================
// Wave = 16 nodes = one 16x64 MFMA A-tile. Only idxv[16] is kept live across
// the prefetch; each element is pinned with an empty asm so the compiler
// cannot sink the 16 independent index loads into the per-node loop.

__device__ __forceinline__ void gather16(const uint2* __restrict__ gf2,
                                         const int* __restrict__ rowptr,
                                         const int* __restrict__ csr,
                                         const float* __restrict__ dinv,
                                         const float4 b4, int n0, int lane,
                                         _Float16* __restrict__ tl) {
    const int g = lane >> 4, p = lane & 15;
    const int rp = rowptr[n0 + min(lane, 16)];
    int idxv[16];
    int end_prev = __shfl(rp, 0, 64);
#pragma unroll
    for (int i = 0; i < 16; ++i) {     // 16 independent index loads in flight
        int beg = end_prev;
        end_prev = __shfl(rp, i + 1, 64);
        idxv[i] = csr[beg + lane];     // safe: csr padded by 64
    }
#pragma unroll
    for (int i = 0; i < 16; ++i) asm volatile("" : "+v"(idxv[i]));  // pin
    end_prev = __shfl(rp, 0, 64);
#pragma unroll
    for (int i = 0; i < 16; ++i) {
        const int beg = end_prev;
        const int end = __shfl(rp, i + 1, 64);
        end_prev = end;
        const int cnt = end - beg;
        const int iv = idxv[i];
        float4 acc = make_float4(0.f, 0.f, 0.f, 0.f);
#pragma unroll
        for (int k = 0; k < 4; ++k) {
            int e = g + 4 * k;
            int s = __shfl(iv, e, 64);
            uint2 u = gf2[(size_t)s * 16 + p];
            __half2 h0 = *(__half2*)&u.x, h1 = *(__half2*)&u.y;
            float2 a = __half22float2(h0), b = __half22float2(h1);
            if (e < cnt) { acc.x += a.x; acc.y += a.y; acc.z += b.x; acc.w += b.y; }
        }
        if (cnt > 16) {
#pragma unroll
            for (int k = 4; k < 8; ++k) {
                int e = g + 4 * k;
                int s = __shfl(iv, e, 64);
                uint2 u = gf2[(size_t)s * 16 + p];
                __half2 h0 = *(__half2*)&u.x, h1 = *(__half2*)&u.y;
                float2 a = __half22float2(h0), b = __half22float2(h1);
                if (e < cnt) { acc.x += a.x; acc.y += a.y; acc.z += b.x; acc.w += b.y; }
            }
            if (cnt > 32) {          // rare tail
                for (int e = 32 + g; e < cnt; e += 4) {
                    int s = (e < 64) ? __shfl(iv, e, 64) : csr[beg + e];
                    uint2 u = gf2[(size_t)s * 16 + p];
                    __half2 h0 = *(__half2*)&u.x, h1 = *(__half2*)&u.y;
                    float2 a = __half22float2(h0), b = __half22float2(h1);
                    acc.x += a.x; acc.y += a.y; acc.z += b.x; acc.w += b.y;
                }
            }
        }
        acc.x += __shfl_xor(acc.x, 16, 64);
        acc.y += __shfl_xor(acc.y, 16, 64);
        acc.z += __shfl_xor(acc.z, 16, 64);
        acc.w += __shfl_xor(acc.w, 16, 64);
        acc.x += __shfl_xor(acc.x, 32, 64);
        acc.y += __shfl_xor(acc.y, 32, 64);
        acc.z += __shfl_xor(acc.z, 32, 64);
        acc.w += __shfl_xor(acc.w, 32, 64);
        if (g == 0) {
            float di = dinv[n0 + i];
            half4_t hv;
            hv[0] = (_Float16)fmaxf(fmaf(di, acc.x, b4.x), 0.0f);
            hv[1] = (_Float16)fmaxf(fmaf(di, acc.y, b4.y), 0.0f);
            hv[2] = (_Float16)fmaxf(fmaf(di, acc.z, b4.z), 0.0f);
            hv[3] = (_Float16)fmaxf(fmaf(di, acc.w, b4.w), 0.0f);
            *(half4_t*)(tl + i * 72 + p * 4) = hv;   // ds_write_b64
        }
    }
}

__global__ __launch_bounds__(256, 3)
void fused_layer_kernel(const __half* __restrict__ gf_in, const int* __restrict__ rowptr,
                        const int* __restrict__ csr, const float* __restrict__ dinv,
                        const float* __restrict__ bprev, const float* __restrict__ W,
                        __half* __restrict__ gf_out) {
    __shared__ __align__(16) _Float16 tile[4][16 * 72];
    const int lane = threadIdx.x & 63, wid = threadIdx.x >> 6;
    const int tid4 = blockIdx.x * 4 + wid;
    if (tid4 >= NTILE) return;
    const int n0 = tid4 * 16;
    _Float16* tl = &tile[wid][0];
    const float4 b4 = ((const float4*)bprev)[lane & 15];

    gather16((const uint2*)gf_in, rowptr, csr, dinv, b4, n0, lane, tl);

    // B-frags: W[k][c] fp32 -> f16, k = kg*8+j (+32 for K-half 1), c = t*16+n
    const int kg = lane >> 4, n = lane & 15;
    half8_t B[4][2];
#pragma unroll
    for (int t = 0; t < 4; ++t)
#pragma unroll
        for (int h = 0; h < 2; ++h)
#pragma unroll
            for (int j = 0; j < 8; ++j)
                B[t][h][j] = (_Float16)W[(h * 32 + kg * 8 + j) * HID + t * 16 + n];

    half8_t A0 = *(const half8_t*)(tl + n * 72 + kg * 8);
    half8_t A1 = *(const half8_t*)(tl + n * 72 + 32 + kg * 8);

    f32x4_t C[4];
#pragma unroll
    for (int t = 0; t < 4; ++t) {
        f32x4_t c = {0.f, 0.f, 0.f, 0.f};
        c = __builtin_amdgcn_mfma_f32_16x16x32_f16(A0, B[t][0], c, 0, 0, 0);
        c = __builtin_amdgcn_mfma_f32_16x16x32_f16(A1, B[t][1], c, 0, 0, 0);
        C[t] = c;
    }

    // epilogue: scale by di[row], fp16, LDS transpose, coalesced stores
    const int q = lane >> 4;
    float di4[4];
#pragma unroll
    for (int r = 0; r < 4; ++r) di4[r] = dinv[n0 + q * 4 + r];
#pragma unroll
    for (int t = 0; t < 4; ++t)
#pragma unroll
        for (int r = 0; r < 4; ++r)
            tl[(q * 4 + r) * 72 + t * 16 + n] = (_Float16)(C[t][r] * di4[r]);
    __builtin_amdgcn_s_waitcnt(0);   // lgkm drain before cross-lane LDS read
    const int r2 = lane >> 2, ch = lane & 3;
    uint4 v0 = *(const uint4*)(tl + r2 * 72 + ch * 16);
    uint4 v1 = *(const uint4*)(tl + r2 * 72 + ch * 16 + 8);
    *(uint4*)((__half*)gf_out + (size_t)(n0 + r2) * HID + ch * 16) = v0;
    *(uint4*)((__half*)gf_out + (size_t)(n0 + r2) * HID + ch * 16 + 8) = v1;
}

// ================= fused final: gather + hv + MFMA (Wm1) + head =================

__global__ __launch_bounds__(256, 3)
void fused_final_kernel(const __half* __restrict__ gf_in, const int* __restrict__ rowptr,
                        const int* __restrict__ csr, const float* __restrict__ dinv,
                        const float* __restrict__ b3, const float* __restrict__ Wm1,
                        const float* __restrict__ bm1, const float* __restrict__ Wm2,
                        const float* __restrict__ bm2, float* __restrict__ out) {
    __shared__ __align__(16) _Float16 tile[4][16 * 72];
    const int lane = threadIdx.x & 63, wid = threadIdx.x >> 6;
    const int tid4 = blockIdx.x * 4 + wid;
    if (tid4 >= NTILE) return;
    const int n0 = tid4 * 16;
    _Float16* tl = &tile[wid][0];
    const float4 b4 = ((const float4*)b3)[lane & 15];

    gather16((const uint2*)gf_in, rowptr, csr, dinv, b4, n0, lane, tl);

    const int kg = lane >> 4, n = lane & 15;
    half8_t B[4][2];
#pragma unroll
    for (int t = 0; t < 4; ++t)
#pragma unroll
        for (int h = 0; h < 2; ++h)
#pragma unroll
            for (int j = 0; j < 8; ++j)
                B[t][h][j] = (_Float16)Wm1[(h * 32 + kg * 8 + j) * HID + t * 16 + n];

    half8_t A0 = *(const half8_t*)(tl + n * 72 + kg * 8);
    half8_t A1 = *(const half8_t*)(tl + n * 72 + 32 + kg * 8);

    f32x4_t C[4];
#pragma unroll
    for (int t = 0; t < 4; ++t) {
        f32x4_t c = {0.f, 0.f, 0.f, 0.f};
        c = __builtin_amdgcn_mfma_f32_16x16x32_f16(A0, B[t][0], c, 0, 0, 0);
        c = __builtin_amdgcn_mfma_f32_16x16x32_f16(A1, B[t][1], c, 0, 0, 0);
        C[t] = c;
    }

    // head: m = relu(C + bm1[c]); part[r] = sum_c m*Wm2[c]; reduce over n-lanes
    float bm14[4], wm24[4];
#pragma unroll
    for (int t = 0; t < 4; ++t) { bm14[t] = bm1[t * 16 + n]; wm24[t] = Wm2[t * 16 + n]; }
    const float bm20 = bm2[0];
    float part[4] = {0.f, 0.f, 0.f, 0.f};
#pragma unroll
    for (int t = 0; t < 4; ++t)
#pragma unroll
        for (int r = 0; r < 4; ++r)
            part[r] += fmaxf(C[t][r] + bm14[t], 0.0f) * wm24[t];
#pragma unroll
    for (int off = 1; off < 16; off <<= 1)
#pragma unroll
        for (int r = 0; r < 4; ++r) part[r] += __shfl_xor(part[r], off, 64);
    if (n == 0) {
        const int q = lane >> 4;
#pragma unroll
        for (int r = 0; r < 4; ++r)
            out[n0 + q * 4 + r] = 1.0f / (1.0f + expf(-(part[r] + bm20)));
    }
}

// ---------------- launch ----------------

extern "C" void kernel_launch(void* const* d_in, const int* in_sizes, int n_in,
                              void* d_out, int out_size, void* d_ws, size_t ws_size,
                              hipStream_t stream) {
    const float* x   = (const float*)d_in[0];
    const int*   ei  = (const int*)d_in[1];
    const float* W1  = (const float*)d_in[2];
    const float* b1  = (const float*)d_in[3];
    const float* W2  = (const float*)d_in[4];
    const float* b2  = (const float*)d_in[5];
    const float* W3  = (const float*)d_in[6];
    const float* b3  = (const float*)d_in[7];
    const float* Wm1 = (const float*)d_in[8];
    const float* bm1 = (const float*)d_in[9];
    const float* Wm2 = (const float*)d_in[10];
    const float* bm2 = (const float*)d_in[11];
    float* out = (float*)d_out;

    const int* src = ei;
    const int* dst = ei + N_EDGES;

    char* ws = (char*)d_ws;
    size_t off = 0;
    auto alloc = [&](size_t bytes) { size_t o = off; off = (off + bytes + 255) & ~(size_t)255; return (void*)(ws + o); };
    int*    rowptr = (int*)alloc(4ll * (N_NODES + 1));
    int*    bsumA  = (int*)alloc(4ll * NHB);
    int*    histA  = (int*)alloc(4ll * NHIST);
    int*    baseA  = (int*)alloc(4ll * (NHIST + 1));
    int*    csr    = (int*)alloc(4ll * (EP + 64));       // +64 pad (zeros)
    float*  dinv   = (float*)alloc(4ll * N_NODES);
    __half* gfA    = (__half*)alloc(2ll * N_NODES * HID);
    __half* gfB    = (__half*)alloc(2ll * N_NODES * HID);
    u64*    ebuf   = (u64*)alloc(8ll * N_EDGES);
    (void)ws_size;

    // --- CSR build: 6 dispatches, zero global atomics ---
    hist_kernel<<<NCHUNK, 256, 0, stream>>>(dst, histA, csr);
    scang_block<<<NHB, SCAN_B, 0, stream>>>(histA, baseA, bsumA, NHIST);
    scang_bsum<<<1, 256, 0, stream>>>(bsumA, NHB);
    scang_add<<<NHB, SCAN_B, 0, stream>>>(baseA, bsumA, NHIST);
    scatter_kernel<<<NCHUNK, 256, 0, stream>>>(src, dst, baseA, ebuf);
    rankfill_kernel<<<NBUCK, 256, 0, stream>>>(ebuf, baseA, rowptr, csr, dinv);

    // --- layers (fused gather + MFMA transform) ---
    const int fblocks = (NTILE + 3) / 4;   // 1563
    layer1_kernel<<<(N_NODES * HID + 255) / 256, 256, 0, stream>>>(x, W1, dinv, gfA);
    fused_layer_kernel<<<fblocks, 256, 0, stream>>>(gfA, rowptr, csr, dinv, b1, W2, gfB);
    fused_layer_kernel<<<fblocks, 256, 0, stream>>>(gfB, rowptr, csr, dinv, b2, W3, gfA);
    fused_final_kernel<<<fblocks, 256, 0, stream>>>(gfA, rowptr, csr, dinv, b3, Wm1, bm1, Wm2, bm2, out);
}

// Round 11
// 292.810 us; speedup vs baseline: 1.3030x; 1.2425x over previous
//
#include <hip/hip_runtime.h>
#include <hip/hip_fp16.h>
#include <math.h>

#define N_NODES 100000
#define N_EDGES 1600000
#define EP (N_EDGES + N_NODES)   // edges incl self-loops
#define HID 64
#define SCAN_B 1024
#define NCHUNK 512                               // pass-A chunks
#define CE (N_EDGES / NCHUNK)                    // 3125 edges per chunk (exact)
#define NBUCK 391                                // buckets of 256 keys
#define NHIST (NBUCK * NCHUNK)                   // 200192
#define NHB ((NHIST + SCAN_B - 1) / SCAN_B)      // 196 blocks (hist scan)
#define NTILE (N_NODES / 16)                     // 6250 MFMA tiles (exact)
#define STASH 6144                               // per-bucket edge stash (avg 4092)
#define NPN 8    // nodes per wave (gather) — 24 live ints: survives regalloc (R8-proven)

typedef _Float16 half8_t __attribute__((ext_vector_type(8)));
typedef float f32x4_t __attribute__((ext_vector_type(4)));
typedef unsigned long long u64;

// ================= bucketed CSR build (no global atomics) =================

__global__ __launch_bounds__(256)
void hist_kernel(const int* __restrict__ dst, int* __restrict__ h, int* __restrict__ csr) {
    __shared__ int hist[NBUCK];
    const int tid = threadIdx.x, c = blockIdx.x;
    for (int b = tid; b < NBUCK; b += 256) hist[b] = 0;
    __syncthreads();
    for (int e = c * CE + tid; e < (c + 1) * CE; e += 256)
        atomicAdd(&hist[dst[e] >> 8], 1);
    __syncthreads();
    for (int b = tid; b < NBUCK; b += 256) h[b * NCHUNK + c] = hist[b];
    if (c == 0 && tid < 64) csr[EP + tid] = 0;   // zero pad for gather over-read
}

__global__ void scang_block(const int* __restrict__ in, int* __restrict__ out,
                            int* __restrict__ bsum, int n) {
    __shared__ int wsum[16];
    int tid = threadIdx.x, lane = tid & 63, wid = tid >> 6;
    int i = blockIdx.x * SCAN_B + tid;
    int x = (i < n) ? in[i] : 0;
#pragma unroll
    for (int off = 1; off < 64; off <<= 1) {
        int y = __shfl_up(x, off, 64);
        if (lane >= off) x += y;
    }
    if (lane == 63) wsum[wid] = x;
    __syncthreads();
    if (tid == 0) {
        int s = 0;
#pragma unroll
        for (int j = 0; j < 16; ++j) { int t2 = wsum[j]; wsum[j] = s; s += t2; }
    }
    __syncthreads();
    int inc = wsum[wid] + x;
    if (i < n) out[i + 1] = inc;
    if (tid == SCAN_B - 1) bsum[blockIdx.x] = inc;
}

__global__ void scang_bsum(int* __restrict__ bsum, int nb) {   // nb <= 256
    __shared__ int tmp[256];
    int t = threadIdx.x;
    tmp[t] = (t < nb) ? bsum[t] : 0;
    __syncthreads();
    for (int off = 1; off < 256; off <<= 1) {
        int v = (t >= off) ? tmp[t - off] : 0;
        __syncthreads();
        tmp[t] += v;
        __syncthreads();
    }
    if (t < nb) bsum[t] = (t == 0) ? 0 : tmp[t - 1];
}

__global__ void scang_add(int* __restrict__ out, const int* __restrict__ bsum, int n) {
    int i = blockIdx.x * SCAN_B + threadIdx.x;
    if (i == 0) out[0] = 0;
    if (i < n) out[i + 1] += bsum[blockIdx.x];
}

__global__ __launch_bounds__(256)
void scatter_kernel(const int* __restrict__ src, const int* __restrict__ dst,
                    const int* __restrict__ baseA, u64* __restrict__ ebuf) {
    __shared__ int cur[NBUCK];
    const int tid = threadIdx.x, c = blockIdx.x;
    for (int b = tid; b < NBUCK; b += 256) cur[b] = baseA[b * NCHUNK + c];
    __syncthreads();
    for (int e = c * CE + tid; e < (c + 1) * CE; e += 256) {
        int d = dst[e], s = src[e];
        int p = atomicAdd(&cur[d >> 8], 1);
        ebuf[p] = (u64)(unsigned)d | ((u64)(unsigned)s << 32);
    }
}

// rankfill: per-bucket rank + cnt block-scan -> rowptr, csr (edges + self-loop), dinv

__global__ __launch_bounds__(256)
void rankfill_kernel(u64* __restrict__ ebuf, const int* __restrict__ baseA,
                     int* __restrict__ rowptr, int* __restrict__ csr,
                     float* __restrict__ dinv) {
    __shared__ int cnt[256];
    __shared__ int rpl[256];
    __shared__ int wsum[4];
    __shared__ u64 stash[STASH];
    const int tid = threadIdx.x, b = blockIdx.x;
    cnt[tid] = 0;
    __syncthreads();
    const int R0 = baseA[b * NCHUNK], R1 = baseA[(b + 1) * NCHUNK];
    const int RL = R1 - R0;
    for (int off = tid; off < RL; off += 256) {
        u64 v = ebuf[R0 + off];
        int d = (int)(unsigned)v;
        int s = (int)(v >> 32);
        int key = d & 255;
        int r = atomicAdd(&cnt[key], 1);
        u64 packed = (u64)(unsigned)s | ((u64)key << 32) | ((u64)r << 40);
        if (off < STASH) stash[off] = packed;
        else ebuf[R0 + off] = packed;   // overflow fallback (≈ never)
    }
    __threadfence_block();
    __syncthreads();
    const int lane = tid & 63, w = tid >> 6;
    int x = cnt[tid];
    int inc = x;
#pragma unroll
    for (int off = 1; off < 64; off <<= 1) {
        int y = __shfl_up(inc, off, 64);
        if (lane >= off) inc += y;
    }
    if (lane == 63) wsum[w] = inc;
    __syncthreads();
    int base = 0;
    for (int k = 0; k < 4; ++k) if (k < w) base += wsum[k];
    int pre = base + inc - x;            // exclusive prefix
    const int n = b * 256 + tid;
    const int rpn = R0 + n + pre;
    rpl[tid] = rpn;
    if (n < N_NODES) {
        rowptr[n] = rpn;
        dinv[n] = rsqrtf((float)(x + 1));
        csr[rpn + x] = n;                // self-loop at end of node's list
    }
    if (b == NBUCK - 1 && tid == 0) rowptr[N_NODES] = EP;
    __syncthreads();
    for (int off = tid; off < RL; off += 256) {
        u64 pk = (off < STASH) ? stash[off] : ebuf[R0 + off];
        int s = (int)(unsigned)pk;
        int key = (int)((pk >> 32) & 0xff);
        int r = (int)(pk >> 40);
        csr[rpl[key] + r] = s;
    }
}

// ---------------- layer 1: gf = fp16( dinv * (x @ W1) ), [N][64] ----------------

__global__ void layer1_kernel(const float* __restrict__ x, const float* __restrict__ W1,
                              const float* __restrict__ dinv, __half* __restrict__ gf) {
    int idx = blockIdx.x * blockDim.x + threadIdx.x;
    if (idx >= N_NODES * HID) return;
    int n = idx >> 6, c = idx & 63;
    float v = x[n * 3 + 0] * W1[c] + x[n * 3 + 1] * W1[HID + c]
            + x[n * 3 + 2] * W1[2 * HID + c];
    gf[idx] = __float2half(v * dinv[n]);
}

// ---------------- gather (R8-proven): full-feature pull, agg[n] = sum over CSR ----------------

__global__ __launch_bounds__(256)
void gather_kernel(const __half* __restrict__ gf, const int* __restrict__ rowptr,
                   const int* __restrict__ csr, float* __restrict__ agg) {
    const int lane = threadIdx.x & 63, wid = threadIdx.x >> 6;
    const int g = lane >> 4, p = lane & 15;
    const int n0 = (blockIdx.x * 4 + wid) * NPN;
    int rp = rowptr[n0 + min(lane, NPN)];   // 9 lanes valid
    const uint2* gf2 = (const uint2*)gf;    // node s slice p -> gf2[s*16+p]
    int begv[NPN], cntv[NPN], idxv[NPN];
    int end_prev = __shfl(rp, 0, 64);
#pragma unroll
    for (int i = 0; i < NPN; ++i) {         // 8 independent index loads in flight
        int end = __shfl(rp, i + 1, 64);
        begv[i] = end_prev;
        cntv[i] = end - end_prev;
        end_prev = end;
        idxv[i] = csr[begv[i] + lane];      // safe: csr padded by 64
    }
#pragma unroll
    for (int i = 0; i < NPN; ++i) {
        const int n = n0 + i;
        const int cnt = cntv[i], beg = begv[i], iv = idxv[i];
        float4 acc = make_float4(0.f, 0.f, 0.f, 0.f);
#pragma unroll
        for (int k = 0; k < 4; ++k) {
            int e = g + 4 * k;
            int s = __shfl(iv, e, 64);
            uint2 u = gf2[(size_t)s * 16 + p];
            __half2 h0 = *(__half2*)&u.x, h1 = *(__half2*)&u.y;
            float2 a = __half22float2(h0), b = __half22float2(h1);
            if (e < cnt) { acc.x += a.x; acc.y += a.y; acc.z += b.x; acc.w += b.y; }
        }
        if (cnt > 16) {
#pragma unroll
            for (int k = 4; k < 8; ++k) {
                int e = g + 4 * k;
                int s = __shfl(iv, e, 64);
                uint2 u = gf2[(size_t)s * 16 + p];
                __half2 h0 = *(__half2*)&u.x, h1 = *(__half2*)&u.y;
                float2 a = __half22float2(h0), b = __half22float2(h1);
                if (e < cnt) { acc.x += a.x; acc.y += a.y; acc.z += b.x; acc.w += b.y; }
            }
            if (cnt > 32) {          // rare tail
                for (int e = 32 + g; e < cnt; e += 4) {
                    int s = (e < 64) ? __shfl(iv, e, 64) : csr[beg + e];
                    uint2 u = gf2[(size_t)s * 16 + p];
                    __half2 h0 = *(__half2*)&u.x, h1 = *(__half2*)&u.y;
                    float2 a = __half22float2(h0), b = __half22float2(h1);
                    acc.x += a.x; acc.y += a.y; acc.z += b.x; acc.w += b.y;
                }
            }
        }
        acc.x += __shfl_xor(acc.x, 16, 64);
        acc.y += __shfl_xor(acc.y, 16, 64);
        acc.z += __shfl_xor(acc.z, 16, 64);
        acc.w += __shfl_xor(acc.w, 16, 64);
        acc.x += __shfl_xor(acc.x, 32, 64);
        acc.y += __shfl_xor(acc.y, 32, 64);
        acc.z += __shfl_xor(acc.z, 32, 64);
        acc.w += __shfl_xor(acc.w, 32, 64);
        if (g == 0) ((float4*)(agg + (size_t)n * HID))[p] = acc;
    }
}

// ================= MFMA transform: hv = relu(di*agg+b); gf_out = fp16(di*(hv@W)) =================
// Wave = one 16x64 tile. Lane loads 16 floats of agg (row r=lane>>2, colgroup
// cg=lane&3), computes fp16 hv into wave-private LDS tile (stride 72), then
// A-frags from LDS + B-frags (W fp32->f16, VGPR) -> 8 MFMA -> scaled epilogue.

__device__ __forceinline__ void hv_to_tile(const float* __restrict__ agg,
                                           const float* __restrict__ dinv,
                                           const float* __restrict__ bprev,
                                           int n0, int lane, _Float16* __restrict__ tl) {
    const int r = lane >> 2, cg = lane & 3;
    const float dr = dinv[n0 + r];
    const float4* arow = (const float4*)(agg + (size_t)(n0 + r) * HID + cg * 16);
    const float4* brow = (const float4*)(bprev + cg * 16);
    float4 a0 = arow[0], a1 = arow[1], a2 = arow[2], a3 = arow[3];
    float4 b0 = brow[0], b1 = brow[1], b2 = brow[2], b3 = brow[3];
    half8_t h0, h1;
    h0[0] = (_Float16)fmaxf(fmaf(dr, a0.x, b0.x), 0.f);
    h0[1] = (_Float16)fmaxf(fmaf(dr, a0.y, b0.y), 0.f);
    h0[2] = (_Float16)fmaxf(fmaf(dr, a0.z, b0.z), 0.f);
    h0[3] = (_Float16)fmaxf(fmaf(dr, a0.w, b0.w), 0.f);
    h0[4] = (_Float16)fmaxf(fmaf(dr, a1.x, b1.x), 0.f);
    h0[5] = (_Float16)fmaxf(fmaf(dr, a1.y, b1.y), 0.f);
    h0[6] = (_Float16)fmaxf(fmaf(dr, a1.z, b1.z), 0.f);
    h0[7] = (_Float16)fmaxf(fmaf(dr, a1.w, b1.w), 0.f);
    h1[0] = (_Float16)fmaxf(fmaf(dr, a2.x, b2.x), 0.f);
    h1[1] = (_Float16)fmaxf(fmaf(dr, a2.y, b2.y), 0.f);
    h1[2] = (_Float16)fmaxf(fmaf(dr, a2.z, b2.z), 0.f);
    h1[3] = (_Float16)fmaxf(fmaf(dr, a2.w, b2.w), 0.f);
    h1[4] = (_Float16)fmaxf(fmaf(dr, a3.x, b3.x), 0.f);
    h1[5] = (_Float16)fmaxf(fmaf(dr, a3.y, b3.y), 0.f);
    h1[6] = (_Float16)fmaxf(fmaf(dr, a3.z, b3.z), 0.f);
    h1[7] = (_Float16)fmaxf(fmaf(dr, a3.w, b3.w), 0.f);
    *(half8_t*)(tl + r * 72 + cg * 16) = h0;
    *(half8_t*)(tl + r * 72 + cg * 16 + 8) = h1;
}

__global__ __launch_bounds__(256, 3)
void mfma_transform_kernel(const float* __restrict__ agg, const float* __restrict__ dinv,
                           const float* __restrict__ bprev, const float* __restrict__ W,
                           __half* __restrict__ gf_out) {
    __shared__ __align__(16) _Float16 tile[4][16 * 72];
    const int lane = threadIdx.x & 63, wid = threadIdx.x >> 6;
    const int tid4 = blockIdx.x * 4 + wid;
    if (tid4 >= NTILE) return;
    const int n0 = tid4 * 16;
    _Float16* tl = &tile[wid][0];

    hv_to_tile(agg, dinv, bprev, n0, lane, tl);

    // B-frags: W[k][c] fp32 -> f16, k = kg*8+j (+32 for K-half 1), c = t*16+n
    const int kg = lane >> 4, n = lane & 15;
    half8_t B[4][2];
#pragma unroll
    for (int t = 0; t < 4; ++t)
#pragma unroll
        for (int h = 0; h < 2; ++h)
#pragma unroll
            for (int j = 0; j < 8; ++j)
                B[t][h][j] = (_Float16)W[(h * 32 + kg * 8 + j) * HID + t * 16 + n];

    __builtin_amdgcn_s_waitcnt(0);   // drain lgkm before cross-lane LDS read
    half8_t A0 = *(const half8_t*)(tl + n * 72 + kg * 8);
    half8_t A1 = *(const half8_t*)(tl + n * 72 + 32 + kg * 8);

    f32x4_t C[4];
#pragma unroll
    for (int t = 0; t < 4; ++t) {
        f32x4_t c = {0.f, 0.f, 0.f, 0.f};
        c = __builtin_amdgcn_mfma_f32_16x16x32_f16(A0, B[t][0], c, 0, 0, 0);
        c = __builtin_amdgcn_mfma_f32_16x16x32_f16(A1, B[t][1], c, 0, 0, 0);
        C[t] = c;
    }

    // epilogue: scale by di[row], fp16, LDS transpose, coalesced stores
    const int q = lane >> 4;
    float di4[4];
#pragma unroll
    for (int r = 0; r < 4; ++r) di4[r] = dinv[n0 + q * 4 + r];
#pragma unroll
    for (int t = 0; t < 4; ++t)
#pragma unroll
        for (int r = 0; r < 4; ++r)
            tl[(q * 4 + r) * 72 + t * 16 + n] = (_Float16)(C[t][r] * di4[r]);
    __builtin_amdgcn_s_waitcnt(0);
    const int r2 = lane >> 2, ch = lane & 3;
    uint4 v0 = *(const uint4*)(tl + r2 * 72 + ch * 16);
    uint4 v1 = *(const uint4*)(tl + r2 * 72 + ch * 16 + 8);
    *(uint4*)((__half*)gf_out + (size_t)(n0 + r2) * HID + ch * 16) = v0;
    *(uint4*)((__half*)gf_out + (size_t)(n0 + r2) * HID + ch * 16 + 8) = v1;
}

// ================= MFMA final: hv + MFMA (Wm1) + head + sigmoid =================

__global__ __launch_bounds__(256, 3)
void mfma_final_kernel(const float* __restrict__ agg, const float* __restrict__ dinv,
                       const float* __restrict__ b3, const float* __restrict__ Wm1,
                       const float* __restrict__ bm1, const float* __restrict__ Wm2,
                       const float* __restrict__ bm2, float* __restrict__ out) {
    __shared__ __align__(16) _Float16 tile[4][16 * 72];
    const int lane = threadIdx.x & 63, wid = threadIdx.x >> 6;
    const int tid4 = blockIdx.x * 4 + wid;
    if (tid4 >= NTILE) return;
    const int n0 = tid4 * 16;
    _Float16* tl = &tile[wid][0];

    hv_to_tile(agg, dinv, b3, n0, lane, tl);

    const int kg = lane >> 4, n = lane & 15;
    half8_t B[4][2];
#pragma unroll
    for (int t = 0; t < 4; ++t)
#pragma unroll
        for (int h = 0; h < 2; ++h)
#pragma unroll
            for (int j = 0; j < 8; ++j)
                B[t][h][j] = (_Float16)Wm1[(h * 32 + kg * 8 + j) * HID + t * 16 + n];

    __builtin_amdgcn_s_waitcnt(0);
    half8_t A0 = *(const half8_t*)(tl + n * 72 + kg * 8);
    half8_t A1 = *(const half8_t*)(tl + n * 72 + 32 + kg * 8);

    f32x4_t C[4];
#pragma unroll
    for (int t = 0; t < 4; ++t) {
        f32x4_t c = {0.f, 0.f, 0.f, 0.f};
        c = __builtin_amdgcn_mfma_f32_16x16x32_f16(A0, B[t][0], c, 0, 0, 0);
        c = __builtin_amdgcn_mfma_f32_16x16x32_f16(A1, B[t][1], c, 0, 0, 0);
        C[t] = c;
    }

    // head: m = relu(C + bm1[c]); part[r] = sum_c m*Wm2[c]; reduce over n-lanes
    float bm14[4], wm24[4];
#pragma unroll
    for (int t = 0; t < 4; ++t) { bm14[t] = bm1[t * 16 + n]; wm24[t] = Wm2[t * 16 + n]; }
    const float bm20 = bm2[0];
    float part[4] = {0.f, 0.f, 0.f, 0.f};
#pragma unroll
    for (int t = 0; t < 4; ++t)
#pragma unroll
        for (int r = 0; r < 4; ++r)
            part[r] += fmaxf(C[t][r] + bm14[t], 0.0f) * wm24[t];
#pragma unroll
    for (int off = 1; off < 16; off <<= 1)
#pragma unroll
        for (int r = 0; r < 4; ++r) part[r] += __shfl_xor(part[r], off, 64);
    if (n == 0) {
        const int q = lane >> 4;
#pragma unroll
        for (int r = 0; r < 4; ++r)
            out[n0 + q * 4 + r] = 1.0f / (1.0f + expf(-(part[r] + bm20)));
    }
}

// ---------------- launch ----------------

extern "C" void kernel_launch(void* const* d_in, const int* in_sizes, int n_in,
                              void* d_out, int out_size, void* d_ws, size_t ws_size,
                              hipStream_t stream) {
    const float* x   = (const float*)d_in[0];
    const int*   ei  = (const int*)d_in[1];
    const float* W1  = (const float*)d_in[2];
    const float* b1  = (const float*)d_in[3];
    const float* W2  = (const float*)d_in[4];
    const float* b2  = (const float*)d_in[5];
    const float* W3  = (const float*)d_in[6];
    const float* b3  = (const float*)d_in[7];
    const float* Wm1 = (const float*)d_in[8];
    const float* bm1 = (const float*)d_in[9];
    const float* Wm2 = (const float*)d_in[10];
    const float* bm2 = (const float*)d_in[11];
    float* out = (float*)d_out;

    const int* src = ei;
    const int* dst = ei + N_EDGES;

    char* ws = (char*)d_ws;
    size_t off = 0;
    auto alloc = [&](size_t bytes) { size_t o = off; off = (off + bytes + 255) & ~(size_t)255; return (void*)(ws + o); };
    int*    rowptr = (int*)alloc(4ll * (N_NODES + 1));
    int*    bsumA  = (int*)alloc(4ll * NHB);
    int*    histA  = (int*)alloc(4ll * NHIST);
    int*    baseA  = (int*)alloc(4ll * (NHIST + 1));
    int*    csr    = (int*)alloc(4ll * (EP + 64));       // +64 pad (zeros)
    float*  dinv   = (float*)alloc(4ll * N_NODES);
    __half* gfA    = (__half*)alloc(2ll * N_NODES * HID);
    __half* gfB    = (__half*)alloc(2ll * N_NODES * HID);
    float*  agg    = (float*)alloc(4ll * N_NODES * HID); // fp32 [N][64]
    u64*    ebuf   = (u64*)agg;   // preamble-only, aliases agg (12.8 MB < 25.6 MB)
    (void)ws_size;

    // --- CSR build: 6 dispatches, zero global atomics ---
    hist_kernel<<<NCHUNK, 256, 0, stream>>>(dst, histA, csr);
    scang_block<<<NHB, SCAN_B, 0, stream>>>(histA, baseA, bsumA, NHIST);
    scang_bsum<<<1, 256, 0, stream>>>(bsumA, NHB);
    scang_add<<<NHB, SCAN_B, 0, stream>>>(baseA, bsumA, NHIST);
    scatter_kernel<<<NCHUNK, 256, 0, stream>>>(src, dst, baseA, ebuf);
    rankfill_kernel<<<NBUCK, 256, 0, stream>>>(ebuf, baseA, rowptr, csr, dinv);

    // --- layers (split gather + MFMA transform) ---
    const int gblocks = N_NODES / (4 * NPN);   // 3125, exact
    const int fblocks = (NTILE + 3) / 4;       // 1563
    layer1_kernel<<<(N_NODES * HID + 255) / 256, 256, 0, stream>>>(x, W1, dinv, gfA);
    gather_kernel<<<gblocks, 256, 0, stream>>>(gfA, rowptr, csr, agg);
    mfma_transform_kernel<<<fblocks, 256, 0, stream>>>(agg, dinv, b1, W2, gfB);
    gather_kernel<<<gblocks, 256, 0, stream>>>(gfB, rowptr, csr, agg);
    mfma_transform_kernel<<<fblocks, 256, 0, stream>>>(agg, dinv, b2, W3, gfA);
    gather_kernel<<<gblocks, 256, 0, stream>>>(gfA, rowptr, csr, agg);
    mfma_final_kernel<<<fblocks, 256, 0, stream>>>(agg, dinv, b3, Wm1, bm1, Wm2, bm2, out);
}